// Round 5
// baseline (247.400 us; speedup 1.0000x reference)
//
#include <hip/hip_runtime.h>
#include <hip/hip_cooperative_groups.h>

namespace cg = cooperative_groups;

// PopulationCoding, round 16.
//  r15 post-mortem: fusion gained exactly traffic+launch (-3.5us). Fill
//  forensics: fill dispatch IDs all ==7 mod 15 -> ONE fill/iter, 15
//  dispatches/iter, ~200us rocprof spacing -> our kernels never in top-5.
//  One-fill decomposition forces prep+fused ~= 64us with both < 41.7 ->
//  either prep carries ~20us structural overhead or harness memsets do.
//  r16: the experiment that disambiguates AND wins either way: remove the
//  prep dispatch. Cooperative single kernel: phase1 = split-f16 conversion
//  (blocks 0-255: Wp 64x64 LDS transpose -> Bh/Bl; blocks 256-511: x ->
//  Ah/Al), threadfence + grid.sync(), phase2 = r15 fused GEMM+epi verbatim.
//  Host fallback to the two-kernel path if coop launch is rejected.
// B=1024, IN=512, D=256, P=8, T=32. Output [1024,256] fp32.

constexpr int IN_DIM  = 512;
constexpr int D_DIM   = 256;
constexpr int NTOT    = 2048;   // D*P
constexpr int T_STEPS = 32;

typedef _Float16 f16x8 __attribute__((ext_vector_type(8)));
typedef float    f32x4 __attribute__((ext_vector_type(4)));
typedef ushort   ushort8 __attribute__((ext_vector_type(8)));

#define GLOBAL_AS __attribute__((address_space(1)))
#define LDS_AS    __attribute__((address_space(3)))

__device__ __forceinline__ void split_f16(float v, ushort& h, ushort& l) {
    const _Float16 hf = (_Float16)v;
    const _Float16 lf = (_Float16)((v - (float)hf) * 2048.0f);  // lo pre-scaled 2^11
    h = __builtin_bit_cast(ushort, hf);
    l = __builtin_bit_cast(ushort, lf);
}

// ---------------------------------------------------------------- device body
// Phase-1 helpers shared by coop kernel and fallback prep kernel.
__device__ __forceinline__ void conv_x_body(const float* __restrict__ x,
                                            ushort* __restrict__ Ah,
                                            ushort* __restrict__ Al,
                                            int blk, int t)
{
    const int idx = (blk * 256 + t) * 8;
    float v[8];
    *reinterpret_cast<float4*>(v)     = *reinterpret_cast<const float4*>(x + idx);
    *reinterpret_cast<float4*>(v + 4) = *reinterpret_cast<const float4*>(x + idx + 4);
    __align__(16) ushort h[8], l[8];
#pragma unroll
    for (int j = 0; j < 8; ++j) split_f16(v[j], h[j], l[j]);
    *reinterpret_cast<ushort8*>(Ah + idx) = *reinterpret_cast<const ushort8*>(h);
    *reinterpret_cast<ushort8*>(Al + idx) = *reinterpret_cast<const ushort8*>(l);
}

__device__ __forceinline__ void conv_w_body(const float* __restrict__ Wp,
                                            ushort* __restrict__ Bh,
                                            ushort* __restrict__ Bl,
                                            float (*tile)[69],   // 64x69 scratch
                                            int ib, int t)
{
    const int k0 = (ib >> 5) * 64;          // 8 k-tiles
    const int c0 = (ib & 31) * 64;          // 32 col-tiles
    {
        const int r = t >> 2, cq = (t & 3) * 16;
#pragma unroll
        for (int j = 0; j < 4; ++j)
            *reinterpret_cast<float4*>(&tile[r][cq + j * 4]) =
                *reinterpret_cast<const float4*>(Wp + (size_t)(k0 + r) * NTOT + c0 + cq + j * 4);
    }
    __syncthreads();
    const int rr = t >> 2, kc2 = (t & 3) * 16;
    __align__(16) ushort h[16], l[16];
#pragma unroll
    for (int j = 0; j < 16; ++j) split_f16(tile[kc2 + j][rr], h[j], l[j]);
    ushort* dh = Bh + (size_t)(c0 + rr) * 512 + k0 + kc2;
    ushort* dl = Bl + (size_t)(c0 + rr) * 512 + k0 + kc2;
    *reinterpret_cast<ushort8*>(dh)     = *reinterpret_cast<const ushort8*>(h);
    *reinterpret_cast<ushort8*>(dh + 8) = *reinterpret_cast<const ushort8*>(h + 8);
    *reinterpret_cast<ushort8*>(dl)     = *reinterpret_cast<const ushort8*>(l);
    *reinterpret_cast<ushort8*>(dl + 8) = *reinterpret_cast<const ushort8*>(l + 8);
}

// Phase-2 body (r15 fused GEMM + epilogue, verbatim logic).
template <typename SyncNone>
__device__ __forceinline__ void fused_body(
    const ushort* __restrict__ Ah_g, const ushort* __restrict__ Al_g,
    const ushort* __restrict__ Bh_g, const ushort* __restrict__ Bl_g,
    const float* __restrict__ bp, const float* __restrict__ thrs,
    const float* __restrict__ rateW, const float* __restrict__ rateB,
    const float* __restrict__ c1w, const float* __restrict__ c1b,
    const float* __restrict__ c2w, const float* __restrict__ c2b,
    const float* __restrict__ fus, float* __restrict__ out,
    ushort (*Lds)[4][64][32],          // [2][4][64][32]
    float (*Itile)[65],                // [64][65]
    float* lutf,                       // 384 floats
    float* wlds,                       // 96 floats
    SyncNone)
{
    const int tid  = threadIdx.x;
    const int w    = tid >> 6;          // wave id = staged plane id
    const int lane = tid & 63;

    // bijective XCD swizzle: 512 = 8 XCDs x 64 contiguous wgs.
    const int wg = (blockIdx.x & 7) * 64 + (blockIdx.x >> 3);
    const int b0 = (wg & 15) * 64;      // M tile (batch rows)
    const int c0 = (wg >> 4) * 64;      // N tile (neuron cols)

    const ushort* gbase = (w == 0) ? Ah_g : (w == 1) ? Al_g : (w == 2) ? Bh_g : Bl_g;
    const int     t0    = (w < 2) ? b0 : c0;
    const int     srow  = lane >> 2;
    const int     schk  = (lane & 3) * 8;     // in halves

    const int wr = (w >> 1) * 32;       // quadrant row origin
    const int wc = (w & 1) * 32;        // quadrant col origin
    const int lr = lane & 15;
    const int lg = lane >> 4;           // k-group / output row group

    const f32x4 zero = {0.f, 0.f, 0.f, 0.f};
    f32x4 acch[2][2] = {{zero, zero}, {zero, zero}};
    f32x4 accl[2][2] = {{zero, zero}, {zero, zero}};

    LDS_AS char* lds0 = (LDS_AS char*)&Lds[0][0][0][0];

    auto stage = [&](int buf, int kt) {
        const int koff = kt * 32 + schk;
#pragma unroll
        for (int i = 0; i < 4; ++i) {
            const ushort* src = gbase + (size_t)(t0 + srow + 16 * i) * 512 + koff;
            const int loff = __builtin_amdgcn_readfirstlane(buf * 16384 + w * 4096 + i * 1024);
            __builtin_amdgcn_global_load_lds((const GLOBAL_AS uint*)src,
                                             (LDS_AS uint*)(lds0 + loff), 16, 0, 0);
        }
    };

    auto compute = [&](int buf) {
        f16x8 ah[2], al[2], bh[2], bl[2];
#pragma unroll
        for (int m = 0; m < 2; ++m) {
            const int row = wr + m * 16 + lr;
            ah[m] = *(const f16x8*)&Lds[buf][0][row][lg * 8];
            al[m] = *(const f16x8*)&Lds[buf][1][row][lg * 8];
        }
#pragma unroll
        for (int n = 0; n < 2; ++n) {
            const int col = wc + n * 16 + lr;
            bh[n] = *(const f16x8*)&Lds[buf][2][col][lg * 8];
            bl[n] = *(const f16x8*)&Lds[buf][3][col][lg * 8];
        }
#pragma unroll
        for (int m = 0; m < 2; ++m)
#pragma unroll
            for (int n = 0; n < 2; ++n) {
                acch[m][n] = __builtin_amdgcn_mfma_f32_16x16x32_f16(ah[m], bh[n], acch[m][n], 0, 0, 0);
                accl[m][n] = __builtin_amdgcn_mfma_f32_16x16x32_f16(al[m], bh[n], accl[m][n], 0, 0, 0);
                accl[m][n] = __builtin_amdgcn_mfma_f32_16x16x32_f16(ah[m], bl[n], accl[m][n], 0, 0, 0);
            }
    };

    // ---- prologue: wlds + first stage; LUT build overlaps load latency ----
    if (tid < 96) wlds[tid] = c1w[tid];
    stage(0, 0);
    __syncthreads();                 // wlds visible; buf0 staged (vmcnt drained)

    for (int e = tid; e < 384; e += 256) {
        const int k  = e >> 7;           // tap 0..2
        const int j  = (e >> 6) & 1;     // p-half
        const int nb = (e >> 2) & 15;    // nibble
        const int c  = e & 3;            // channel
        float v = (k == 1 && j == 0) ? c1b[c] : 0.f;  // fold conv1 bias once
#pragma unroll
        for (int p = 0; p < 4; ++p)
            v = fmaf((float)((nb >> p) & 1), wlds[(c * 8 + j * 4 + p) * 3 + k], v);
        lutf[e] = v;
    }

    // ---- GEMM k-loop ----
    for (int kt = 0; kt < 16; ++kt) {
        if (kt < 15) stage((kt + 1) & 1, kt + 1);
        compute(kt & 1);
        __syncthreads();
    }

    // ---- acc -> Itile (C/D layout: col = lane&15, row = (lane>>4)*4 + v) ----
    const float s = 1.0f / 2048.0f;
#pragma unroll
    for (int m = 0; m < 2; ++m)
#pragma unroll
        for (int n = 0; n < 2; ++n)
#pragma unroll
            for (int v = 0; v < 4; ++v)
                Itile[wr + m * 16 + lg * 4 + v][wc + n * 16 + lr] =
                    acch[m][n][v] + accl[m][n][v] * s;
    __syncthreads();

    // ---- uniform scalars ----
    float w2c[4];
#pragma unroll
    for (int c = 0; c < 4; ++c) w2c[c] = c2w[c];
    float rW[8], thrv[8];
#pragma unroll
    for (int p = 0; p < 8; ++p) { rW[p] = rateW[p]; thrv[p] = thrs[p]; }
    const float rb_ = rateB[0];
    const float bb2 = c2b[0];
    const float f0 = fus[0], f1 = fus[1];
    const float fm = fmaxf(f0, f1);
    const float e0 = __expf(f0 - fm), e1 = __expf(f1 - fm);
    const float inv = 1.f / (e0 + e1);
    const float fw0 = e0 * inv, fw1 = e1 * inv;

    // ---- epilogue: 2 full neurons per thread ----
    for (int half = 0; half < 2; ++half) {
        const int nb   = tid + half * 256;   // 0..511
        const int row  = nb >> 3;            // batch-local 0..63
        const int dloc = nb & 7;
        const int dg   = (c0 >> 3) + dloc;   // global d

        const float* ip = &Itile[row][dloc * 8];
        const float4 bv0 = *reinterpret_cast<const float4*>(bp + dg * 8);
        const float4 bv1 = *reinterpret_cast<const float4*>(bp + dg * 8 + 4);
        const float bpx[8] = {bv0.x, bv0.y, bv0.z, bv0.w, bv1.x, bv1.y, bv1.z, bv1.w};

        float Iv[8], Imt[8], mem[8];
        bool  spk[8];
#pragma unroll
        for (int p = 0; p < 8; ++p) {
            Iv[p]  = ip[p] + bpx[p];
            Imt[p] = Iv[p] - thrv[p];
            mem[p] = 0.f;
            spk[p] = false;
        }

        unsigned nibL[4] = {0u, 0u, 0u, 0u}, nibH[4] = {0u, 0u, 0u, 0u};
#pragma unroll
        for (int t = 0; t < T_STEPS; ++t) {
            unsigned bl_ = 0u, bh_ = 0u;
#pragma unroll
            for (int p = 0; p < 8; ++p) {
                mem[p] = 0.95f * mem[p] + (spk[p] ? Imt[p] : Iv[p]);
                spk[p] = mem[p] > thrv[p];
            }
#pragma unroll
            for (int p = 0; p < 4; ++p) bl_ |= spk[p] ? (1u << p) : 0u;
#pragma unroll
            for (int p = 4; p < 8; ++p) bh_ |= spk[p] ? (1u << (p - 4)) : 0u;
            nibL[t >> 3] |= bl_ << (4 * (t & 7));
            nibH[t >> 3] |= bh_ << (4 * (t & 7));
        }

        // rate: exact bit-plane popcount
        float rsum = 0.f;
#pragma unroll
        for (int p = 0; p < 4; ++p) {
            const unsigned m = 0x11111111u << p;
            const int cL = __popc(nibL[0] & m) + __popc(nibL[1] & m)
                         + __popc(nibL[2] & m) + __popc(nibL[3] & m);
            const int cH = __popc(nibH[0] & m) + __popc(nibH[1] & m)
                         + __popc(nibH[2] & m) + __popc(nibH[3] & m);
            rsum = fmaf((float)cL, rW[p], rsum);
            rsum = fmaf((float)cH, rW[4 + p], rsum);
        }

        // conv: full 32-t range, 6 nibble-LUT reads per t
        auto getn = [](const unsigned* a, int t) -> unsigned {
            return (a[t >> 3] >> (4 * (t & 7))) & 15u;
        };
        float tacc = 0.f;
        unsigned nlp = 0u, nhp = 0u;
        unsigned nlc = getn(nibL, 0), nhc = getn(nibH, 0);
#pragma unroll
        for (int t = 0; t < T_STEPS; ++t) {
            const unsigned nln = (t < 31) ? getn(nibL, t + 1) : 0u;
            const unsigned nhn = (t < 31) ? getn(nibH, t + 1) : 0u;
            const float4 a0 = *reinterpret_cast<const float4*>(lutf + (nlp     ) * 4);
            const float4 a1 = *reinterpret_cast<const float4*>(lutf + (nhp + 16) * 4);
            const float4 b0 = *reinterpret_cast<const float4*>(lutf + (nlc + 32) * 4);
            const float4 b1 = *reinterpret_cast<const float4*>(lutf + (nhc + 48) * 4);
            const float4 c0v = *reinterpret_cast<const float4*>(lutf + (nln + 64) * 4);
            const float4 c1v = *reinterpret_cast<const float4*>(lutf + (nhn + 80) * 4);
            const float h0_ = ((a0.x + a1.x) + (b0.x + b1.x)) + (c0v.x + c1v.x);
            const float h1_ = ((a0.y + a1.y) + (b0.y + b1.y)) + (c0v.y + c1v.y);
            const float h2_ = ((a0.z + a1.z) + (b0.z + b1.z)) + (c0v.z + c1v.z);
            const float h3_ = ((a0.w + a1.w) + (b0.w + b1.w)) + (c0v.w + c1v.w);
            tacc = fmaf(fmaxf(h0_, 0.f), w2c[0], tacc);
            tacc = fmaf(fmaxf(h1_, 0.f), w2c[1], tacc);
            tacc = fmaf(fmaxf(h2_, 0.f), w2c[2], tacc);
            tacc = fmaf(fmaxf(h3_, 0.f), w2c[3], tacc);
            nlp = nlc; nhp = nhc; nlc = nln; nhc = nhn;
        }

        const float rdec = rsum * (1.f / 32.f) + rb_;
        const float temp = tacc * (1.f / 32.f) + bb2;
        out[(b0 + row) * D_DIM + dg] = fw0 * rdec + fw1 * temp;
    }
}

// --------------------------------------------- coop kernel: prep + fused
__global__ __launch_bounds__(256, 2)
void popcode_coop(const float* __restrict__ x, const float* __restrict__ Wp,
                  const float* __restrict__ bp, const float* __restrict__ thrs,
                  const float* __restrict__ rateW, const float* __restrict__ rateB,
                  const float* __restrict__ c1w, const float* __restrict__ c1b,
                  const float* __restrict__ c2w, const float* __restrict__ c2b,
                  const float* __restrict__ fus, float* __restrict__ out,
                  ushort* __restrict__ Ah, ushort* __restrict__ Al,
                  ushort* __restrict__ Bh, ushort* __restrict__ Bl)
{
    __shared__ __align__(16) ushort Lds[2][4][64][32];   // 32 KB staging
    __shared__ float Itile[64][65];                      // 16.6 KB
    __shared__ float lut[384];
    __shared__ float wlds[96];

    const int tid = threadIdx.x;

    // ---- phase 1: split-f16 conversion ----
    if (blockIdx.x < 256) {
        float (*tile)[69] = reinterpret_cast<float(*)[69]>(&Lds[0][0][0][0]);  // 17.7 KB scratch
        conv_w_body(Wp, Bh, Bl, tile, blockIdx.x, tid);
    } else {
        conv_x_body(x, Ah, Al, blockIdx.x - 256, tid);
    }

    __threadfence();                 // make phase-1 writes device-visible
    cg::this_grid().sync();

    // ---- phase 2: GEMM + epilogue (r15 verbatim) ----
    fused_body(Ah, Al, Bh, Bl, bp, thrs, rateW, rateB, c1w, c1b, c2w, c2b,
               fus, out, Lds, Itile, lut, wlds, 0);
}

// --------------------------------------------- fallback: two-kernel path
__global__ __launch_bounds__(256)
void popcode_prep(const float* __restrict__ x, const float* __restrict__ Wp,
                  ushort* __restrict__ Ah, ushort* __restrict__ Al,
                  ushort* __restrict__ Bh, ushort* __restrict__ Bl)
{
    __shared__ float tile[64][69];
    const int t = threadIdx.x;
    if (blockIdx.x < 256) conv_x_body(x, Ah, Al, blockIdx.x, t);
    else                  conv_w_body(Wp, Bh, Bl, tile, blockIdx.x - 256, t);
}

__global__ __launch_bounds__(256, 2)
void popcode_fused(const ushort* __restrict__ Ah_g, const ushort* __restrict__ Al_g,
                   const ushort* __restrict__ Bh_g, const ushort* __restrict__ Bl_g,
                   const float* __restrict__ bp, const float* __restrict__ thrs,
                   const float* __restrict__ rateW, const float* __restrict__ rateB,
                   const float* __restrict__ c1w, const float* __restrict__ c1b,
                   const float* __restrict__ c2w, const float* __restrict__ c2b,
                   const float* __restrict__ fus, float* __restrict__ out)
{
    __shared__ __align__(16) ushort Lds[2][4][64][32];
    __shared__ float Itile[64][65];
    __shared__ float lut[384];
    __shared__ float wlds[96];
    fused_body(Ah_g, Al_g, Bh_g, Bl_g, bp, thrs, rateW, rateB, c1w, c1b,
               c2w, c2b, fus, out, Lds, Itile, lut, wlds, 0);
}

extern "C" void kernel_launch(void* const* d_in, const int* in_sizes, int n_in,
                              void* d_out, int out_size, void* d_ws, size_t ws_size,
                              hipStream_t stream) {
    const float* x     = (const float*)d_in[0];
    const float* Wp    = (const float*)d_in[1];
    const float* bp    = (const float*)d_in[2];
    const float* thrs  = (const float*)d_in[3];
    const float* rateW = (const float*)d_in[4];
    const float* rateB = (const float*)d_in[5];
    const float* c1w   = (const float*)d_in[6];
    const float* c1b   = (const float*)d_in[7];
    const float* c2w   = (const float*)d_in[8];
    const float* c2b   = (const float*)d_in[9];
    const float* fus   = (const float*)d_in[10];
    float* out = (float*)d_out;
    float* ws  = (float*)d_ws;

    // ws layout: Ah[1024*512]u16 | Al | Bh[2048*512]u16 | Bl   (12 MB)
    ushort* Ah = reinterpret_cast<ushort*>(ws);
    ushort* Al = Ah + 1024 * 512;
    ushort* Bh = Al + 1024 * 512;
    ushort* Bl = Bh + 2048 * 512;

    void* args[] = { (void*)&x, (void*)&Wp, (void*)&bp, (void*)&thrs,
                     (void*)&rateW, (void*)&rateB, (void*)&c1w, (void*)&c1b,
                     (void*)&c2w, (void*)&c2b, (void*)&fus, (void*)&out,
                     (void*)&Ah, (void*)&Al, (void*)&Bh, (void*)&Bl };
    const hipError_t err = hipLaunchCooperativeKernel(
        reinterpret_cast<const void*>(&popcode_coop),
        dim3(512), dim3(256), args, 0, stream);

    if (err != hipSuccess) {
        // fallback: two-kernel path (r15 behavior)
        popcode_prep<<<dim3(512), dim3(256), 0, stream>>>(x, Wp, Ah, Al, Bh, Bl);
        popcode_fused<<<dim3(512), dim3(256), 0, stream>>>(
            Ah, Al, Bh, Bl, bp, thrs, rateW, rateB, c1w, c1b, c2w, c2b, fus, out);
    }
}

// Round 7
// 145.429 us; speedup vs baseline: 1.7012x; 1.7012x over previous
//
#include <hip/hip_runtime.h>

// PopulationCoding, round 18 (= r17 resubmit; r17 bench died on container
// infra, no counters — same failure mode as r13, which passed on resubmit).
//  r16 post-mortem: coop grid.sync cost ~90us (VALUBusy 10%, MfmaUtil 1.6%,
//  HBM 150GB/s -> all idle spinning). Coop dead. But counters landed: fused
//  body VGPR 68, 51.7KB LDS, Occ 22% (grid 512 = 2 blk/CU).
//  Model: epi is LDS-PIPE-bound: r15 conv = 384 b128 reads/thread
//  (2 neurons x 32t x 6) -> ~18us of ds_read issue across 256 CUs, hidden
//  behind only 8 waves/CU. Fix:
//   - byte LUTs: 3 reads/t (r12==r13 showed conflicts ~ cancel vs count).
//   - tile 64x32, grid 1024 (=4 blk/CU, 16 waves), 1 neuron/thread.
//   - LDS union: lut built in staging buffer post-k-loop -> ~33KB total.
// B=1024, IN=512, D=256, P=8, T=32. Output [1024,256] fp32.

constexpr int D_DIM   = 256;
constexpr int NTOT    = 2048;   // D*P
constexpr int T_STEPS = 32;

typedef _Float16 f16x8 __attribute__((ext_vector_type(8)));
typedef float    f32x4 __attribute__((ext_vector_type(4)));
typedef ushort   ushort8 __attribute__((ext_vector_type(8)));

#define GLOBAL_AS __attribute__((address_space(1)))
#define LDS_AS    __attribute__((address_space(3)))

__device__ __forceinline__ void split_f16(float v, ushort& h, ushort& l) {
    const _Float16 hf = (_Float16)v;
    const _Float16 lf = (_Float16)((v - (float)hf) * 2048.0f);  // lo pre-scaled 2^11
    h = __builtin_bit_cast(ushort, hf);
    l = __builtin_bit_cast(ushort, lf);
}

// ------------------------------------------------- K0: split-f16 conversion
__device__ __forceinline__ void conv_x_body(const float* __restrict__ x,
                                            ushort* __restrict__ Ah,
                                            ushort* __restrict__ Al,
                                            int blk, int t)
{
    const int idx = (blk * 256 + t) * 8;
    float v[8];
    *reinterpret_cast<float4*>(v)     = *reinterpret_cast<const float4*>(x + idx);
    *reinterpret_cast<float4*>(v + 4) = *reinterpret_cast<const float4*>(x + idx + 4);
    __align__(16) ushort h[8], l[8];
#pragma unroll
    for (int j = 0; j < 8; ++j) split_f16(v[j], h[j], l[j]);
    *reinterpret_cast<ushort8*>(Ah + idx) = *reinterpret_cast<const ushort8*>(h);
    *reinterpret_cast<ushort8*>(Al + idx) = *reinterpret_cast<const ushort8*>(l);
}

__device__ __forceinline__ void conv_w_body(const float* __restrict__ Wp,
                                            ushort* __restrict__ Bh,
                                            ushort* __restrict__ Bl,
                                            float (*tile)[69],
                                            int ib, int t)
{
    const int k0 = (ib >> 5) * 64;          // 8 k-tiles
    const int c0 = (ib & 31) * 64;          // 32 col-tiles
    {
        const int r = t >> 2, cq = (t & 3) * 16;
#pragma unroll
        for (int j = 0; j < 4; ++j)
            *reinterpret_cast<float4*>(&tile[r][cq + j * 4]) =
                *reinterpret_cast<const float4*>(Wp + (size_t)(k0 + r) * NTOT + c0 + cq + j * 4);
    }
    __syncthreads();
    const int rr = t >> 2, kc2 = (t & 3) * 16;
    __align__(16) ushort h[16], l[16];
#pragma unroll
    for (int j = 0; j < 16; ++j) split_f16(tile[kc2 + j][rr], h[j], l[j]);
    ushort* dh = Bh + (size_t)(c0 + rr) * 512 + k0 + kc2;
    ushort* dl = Bl + (size_t)(c0 + rr) * 512 + k0 + kc2;
    *reinterpret_cast<ushort8*>(dh)     = *reinterpret_cast<const ushort8*>(h);
    *reinterpret_cast<ushort8*>(dh + 8) = *reinterpret_cast<const ushort8*>(h + 8);
    *reinterpret_cast<ushort8*>(dl)     = *reinterpret_cast<const ushort8*>(l);
    *reinterpret_cast<ushort8*>(dl + 8) = *reinterpret_cast<const ushort8*>(l + 8);
}

__global__ __launch_bounds__(256)
void popcode_prep(const float* __restrict__ x, const float* __restrict__ Wp,
                  ushort* __restrict__ Ah, ushort* __restrict__ Al,
                  ushort* __restrict__ Bh, ushort* __restrict__ Bl)
{
    __shared__ float tile[64][69];
    const int t = threadIdx.x;
    if (blockIdx.x < 256) conv_x_body(x, Ah, Al, blockIdx.x, t);
    else                  conv_w_body(Wp, Bh, Bl, tile, blockIdx.x - 256, t);
}

// ------------------------------------- K1: fused split-f16 MFMA GEMM + epi
// 1024 blocks (XCD-swizzled), 256 threads (4 waves). Tile 64x32, BK=32.
// LDS layout (33664 B): [buf0 12288][buf1 12288][Itile 64x34 f32][wlds 384B]
//   plane offsets in buf: Ah 0 (4KB), Al 4096, Bh 8192 (2KB), Bl 10240.
//   byte-LUT (12KB) built into buf0 region after the k-loop.
__global__ __launch_bounds__(256, 4)
void popcode_fused(const ushort* __restrict__ Ah_g, const ushort* __restrict__ Al_g,
                   const ushort* __restrict__ Bh_g, const ushort* __restrict__ Bl_g,
                   const float* __restrict__ bp, const float* __restrict__ thrs,
                   const float* __restrict__ rateW, const float* __restrict__ rateB,
                   const float* __restrict__ c1w, const float* __restrict__ c1b,
                   const float* __restrict__ c2w, const float* __restrict__ c2b,
                   const float* __restrict__ fus, float* __restrict__ out)
{
    __shared__ __align__(16) char smem[33664];
    LDS_AS char* lds0 = (LDS_AS char*)smem;

    const int tid  = threadIdx.x;
    const int w    = tid >> 6;
    const int lane = tid & 63;

    // bijective XCD swizzle: 1024 = 8 XCDs x 128 contiguous wgs.
    const int wg = ((blockIdx.x & 7) << 7) | (blockIdx.x >> 3);
    const int b0 = (wg & 15) * 64;      // M tile (batch rows)
    const int c0 = (wg >> 4) * 32;      // N tile (neuron cols), 64 tiles

    const ushort* gbase = (w == 0) ? Ah_g : (w == 1) ? Al_g : (w == 2) ? Bh_g : Bl_g;
    const int     t0    = (w < 2) ? b0 : c0;
    const int     srow  = lane >> 2;
    const int     schk  = (lane & 3) * 8;     // in halves
    const int     poff  = (w < 2) ? (w * 4096) : (8192 + (w - 2) * 2048);

    const int wr = (w >> 1) * 32;       // quadrant row origin (A rows)
    const int wc = (w & 1) * 16;        // quadrant col origin (B cols)
    const int lr = lane & 15;
    const int lg = lane >> 4;

    const f32x4 zero = {0.f, 0.f, 0.f, 0.f};
    f32x4 acch[2] = {zero, zero};
    f32x4 accl[2] = {zero, zero};

    auto stage = [&](int buf, int kt) {
        const int koff = kt * 32 + schk;
        const int base = buf * 12288 + poff;
        if (w < 2) {
#pragma unroll
            for (int i = 0; i < 4; ++i) {
                const ushort* src = gbase + (size_t)(t0 + srow + 16 * i) * 512 + koff;
                const int loff = __builtin_amdgcn_readfirstlane(base + i * 1024);
                __builtin_amdgcn_global_load_lds((const GLOBAL_AS uint*)src,
                                                 (LDS_AS uint*)(lds0 + loff), 16, 0, 0);
            }
        } else {
#pragma unroll
            for (int i = 0; i < 2; ++i) {
                const ushort* src = gbase + (size_t)(t0 + srow + 16 * i) * 512 + koff;
                const int loff = __builtin_amdgcn_readfirstlane(base + i * 1024);
                __builtin_amdgcn_global_load_lds((const GLOBAL_AS uint*)src,
                                                 (LDS_AS uint*)(lds0 + loff), 16, 0, 0);
            }
        }
    };

    auto compute = [&](int buf) {
        const int rbase = buf * 12288;
        f16x8 ah[2], al[2], bh, bl;
#pragma unroll
        for (int m = 0; m < 2; ++m) {
            const int row = wr + m * 16 + lr;
            ah[m] = *reinterpret_cast<const f16x8*>(smem + rbase +        row * 64 + lg * 16);
            al[m] = *reinterpret_cast<const f16x8*>(smem + rbase + 4096 + row * 64 + lg * 16);
        }
        {
            const int col = wc + lr;
            bh = *reinterpret_cast<const f16x8*>(smem + rbase +  8192 + col * 64 + lg * 16);
            bl = *reinterpret_cast<const f16x8*>(smem + rbase + 10240 + col * 64 + lg * 16);
        }
#pragma unroll
        for (int m = 0; m < 2; ++m) {
            acch[m] = __builtin_amdgcn_mfma_f32_16x16x32_f16(ah[m], bh, acch[m], 0, 0, 0);
            accl[m] = __builtin_amdgcn_mfma_f32_16x16x32_f16(al[m], bh, accl[m], 0, 0, 0);
            accl[m] = __builtin_amdgcn_mfma_f32_16x16x32_f16(ah[m], bl, accl[m], 0, 0, 0);
        }
    };

    // ---- prologue ----
    float* wlds = (float*)(smem + 33280);
    if (tid < 96) wlds[tid] = c1w[tid];
    stage(0, 0);
    __syncthreads();

    // ---- GEMM k-loop ----
    for (int kt = 0; kt < 16; ++kt) {
        if (kt < 15) stage((kt + 1) & 1, kt + 1);
        compute(kt & 1);
        __syncthreads();
    }

    // ---- build byte LUT in buf0 region (staging dead now) ----
    float* lutf = (float*)smem;          // lut[tap][byte][chan], 3072 floats
    for (int e = tid; e < 3072; e += 256) {
        const int k    = e >> 10;
        const int byte = (e >> 2) & 255;
        const int c    = e & 3;
        float v = (k == 1) ? c1b[c] : 0.f;   // fold conv1 bias into tap 1
#pragma unroll
        for (int p = 0; p < 8; ++p)
            v = fmaf((float)((byte >> p) & 1), wlds[(c * 8 + p) * 3 + k], v);
        lutf[e] = v;
    }

    // ---- acc -> Itile (C/D layout: col = lane&15, row = (lane>>4)*4 + v) ----
    float* it = (float*)(smem + 24576);  // [64][34]
    const float s = 1.0f / 2048.0f;
#pragma unroll
    for (int m = 0; m < 2; ++m)
#pragma unroll
        for (int v = 0; v < 4; ++v)
            it[(wr + m * 16 + lg * 4 + v) * 34 + wc + lr] =
                acch[m][v] + accl[m][v] * s;
    __syncthreads();

    // ---- uniform scalars ----
    float w2c[4];
#pragma unroll
    for (int c = 0; c < 4; ++c) w2c[c] = c2w[c];
    float rW[8], thrv[8];
#pragma unroll
    for (int p = 0; p < 8; ++p) { rW[p] = rateW[p]; thrv[p] = thrs[p]; }
    const float rb_ = rateB[0];
    const float bb2 = c2b[0];
    const float f0 = fus[0], f1 = fus[1];
    const float fm = fmaxf(f0, f1);
    const float e0 = __expf(f0 - fm), e1 = __expf(f1 - fm);
    const float inv = 1.f / (e0 + e1);
    const float fw0 = e0 * inv, fw1 = e1 * inv;

    // ---- epilogue: exactly 1 neuron per thread (64 rows x 4 d) ----
    const int row  = tid >> 2;
    const int dloc = tid & 3;
    const int dg   = (c0 >> 3) + dloc;

    const float* ip  = it + row * 34 + dloc * 8;
    const float4 bv0 = *reinterpret_cast<const float4*>(bp + dg * 8);
    const float4 bv1 = *reinterpret_cast<const float4*>(bp + dg * 8 + 4);
    const float bpx[8] = {bv0.x, bv0.y, bv0.z, bv0.w, bv1.x, bv1.y, bv1.z, bv1.w};

    float Iv[8], Imt[8], mem[8];
    bool  spk[8];
#pragma unroll
    for (int p = 0; p < 8; ++p) {
        Iv[p]  = ip[p] + bpx[p];
        Imt[p] = Iv[p] - thrv[p];
        mem[p] = 0.f;
        spk[p] = false;
    }

    // LIF, packing one byte per t (4 t per u32 word)
    unsigned wrd[8] = {0u, 0u, 0u, 0u, 0u, 0u, 0u, 0u};
#pragma unroll
    for (int t = 0; t < T_STEPS; ++t) {
        unsigned by = 0u;
#pragma unroll
        for (int p = 0; p < 8; ++p) {
            mem[p] = 0.95f * mem[p] + (spk[p] ? Imt[p] : Iv[p]);
            spk[p] = mem[p] > thrv[p];
            by |= spk[p] ? (1u << p) : 0u;
        }
        wrd[t >> 2] |= by << (8 * (t & 3));
    }

    // rate branch: exact bit-plane popcount
    float rsum = 0.f;
#pragma unroll
    for (int p = 0; p < 8; ++p) {
        const unsigned m = 0x01010101u << p;
        int cnt = 0;
#pragma unroll
        for (int q = 0; q < 8; ++q) cnt += __popc(wrd[q] & m);
        rsum = fmaf((float)cnt, rW[p], rsum);
    }

    // temporal conv: 3 byte-LUT reads per t
    auto getb = [&](int t) -> unsigned {
        return (wrd[t >> 2] >> (8 * (t & 3))) & 255u;
    };
    float tacc = 0.f;
    unsigned bprev = 0u;
    unsigned bcur  = getb(0);
#pragma unroll
    for (int t = 0; t < T_STEPS; ++t) {
        const unsigned bnext = (t < 31) ? getb(t + 1) : 0u;
        const float4 fa = *reinterpret_cast<const float4*>(lutf + bprev * 4);
        const float4 fb = *reinterpret_cast<const float4*>(lutf + 1024 + bcur * 4);
        const float4 fc = *reinterpret_cast<const float4*>(lutf + 2048 + bnext * 4);
        const float h0_ = (fa.x + fb.x) + fc.x;
        const float h1_ = (fa.y + fb.y) + fc.y;
        const float h2_ = (fa.z + fb.z) + fc.z;
        const float h3_ = (fa.w + fb.w) + fc.w;
        tacc = fmaf(fmaxf(h0_, 0.f), w2c[0], tacc);
        tacc = fmaf(fmaxf(h1_, 0.f), w2c[1], tacc);
        tacc = fmaf(fmaxf(h2_, 0.f), w2c[2], tacc);
        tacc = fmaf(fmaxf(h3_, 0.f), w2c[3], tacc);
        bprev = bcur;
        bcur  = bnext;
    }

    const float rdec = rsum * (1.f / 32.f) + rb_;
    const float temp = tacc * (1.f / 32.f) + bb2;
    out[(b0 + row) * D_DIM + dg] = fw0 * rdec + fw1 * temp;
}

extern "C" void kernel_launch(void* const* d_in, const int* in_sizes, int n_in,
                              void* d_out, int out_size, void* d_ws, size_t ws_size,
                              hipStream_t stream) {
    const float* x     = (const float*)d_in[0];
    const float* Wp    = (const float*)d_in[1];
    const float* bp    = (const float*)d_in[2];
    const float* thrs  = (const float*)d_in[3];
    const float* rateW = (const float*)d_in[4];
    const float* rateB = (const float*)d_in[5];
    const float* c1w   = (const float*)d_in[6];
    const float* c1b   = (const float*)d_in[7];
    const float* c2w   = (const float*)d_in[8];
    const float* c2b   = (const float*)d_in[9];
    const float* fus   = (const float*)d_in[10];
    float* out = (float*)d_out;
    float* ws  = (float*)d_ws;

    // ws layout: Ah[1024*512]u16 | Al | Bh[2048*512]u16 | Bl   (12 MB)
    ushort* Ah = reinterpret_cast<ushort*>(ws);
    ushort* Al = Ah + 1024 * 512;
    ushort* Bh = Al + 1024 * 512;
    ushort* Bl = Bh + 2048 * 512;

    popcode_prep<<<dim3(512), dim3(256), 0, stream>>>(x, Wp, Ah, Al, Bh, Bl);
    popcode_fused<<<dim3(1024), dim3(256), 0, stream>>>(
        Ah, Al, Bh, Bl, bp, thrs, rateW, rateB, c1w, c1b, c2w, c2b, fus, out);
}

// Round 8
// 122.295 us; speedup vs baseline: 2.0230x; 1.1892x over previous
//
#include <hip/hip_runtime.h>

// PopulationCoding, round 19.
//  r18 post-mortem (FIRST real fused counters): WRITE_SIZE 146MB/dispatch
//  (expected ~1MB), HBM 2.1TB/s, VALUBusy 0.4%, Occ 0.5%, VGPR=64 ->
//  __launch_bounds__(256,4) pushed the allocator to the 64-VGPR tier and it
//  SPILLED the epilogue arrays (~560B/thread scratch). Kernel = scratch-BW
//  bound: 146MB/2.1TB/s ~= 71us = whole duration. r15/r16 at (256,2)/68
//  VGPR showed no such writes.
//  r19 fix: launch_bounds(256) (no wave clamp); drop Imt[8] (fold reset
//  subtract); fold bp add immediately. Keep r17 wins: byte-LUT 3 reads/t,
//  1 neuron/thread, 33KB LDS union, grid 1024, XCD swizzle.
// B=1024, IN=512, D=256, P=8, T=32. Output [1024,256] fp32.

constexpr int D_DIM   = 256;
constexpr int NTOT    = 2048;   // D*P
constexpr int T_STEPS = 32;

typedef _Float16 f16x8 __attribute__((ext_vector_type(8)));
typedef float    f32x4 __attribute__((ext_vector_type(4)));
typedef ushort   ushort8 __attribute__((ext_vector_type(8)));

#define GLOBAL_AS __attribute__((address_space(1)))
#define LDS_AS    __attribute__((address_space(3)))

__device__ __forceinline__ void split_f16(float v, ushort& h, ushort& l) {
    const _Float16 hf = (_Float16)v;
    const _Float16 lf = (_Float16)((v - (float)hf) * 2048.0f);  // lo pre-scaled 2^11
    h = __builtin_bit_cast(ushort, hf);
    l = __builtin_bit_cast(ushort, lf);
}

// ------------------------------------------------- K0: split-f16 conversion
__device__ __forceinline__ void conv_x_body(const float* __restrict__ x,
                                            ushort* __restrict__ Ah,
                                            ushort* __restrict__ Al,
                                            int blk, int t)
{
    const int idx = (blk * 256 + t) * 8;
    float v[8];
    *reinterpret_cast<float4*>(v)     = *reinterpret_cast<const float4*>(x + idx);
    *reinterpret_cast<float4*>(v + 4) = *reinterpret_cast<const float4*>(x + idx + 4);
    __align__(16) ushort h[8], l[8];
#pragma unroll
    for (int j = 0; j < 8; ++j) split_f16(v[j], h[j], l[j]);
    *reinterpret_cast<ushort8*>(Ah + idx) = *reinterpret_cast<const ushort8*>(h);
    *reinterpret_cast<ushort8*>(Al + idx) = *reinterpret_cast<const ushort8*>(l);
}

__device__ __forceinline__ void conv_w_body(const float* __restrict__ Wp,
                                            ushort* __restrict__ Bh,
                                            ushort* __restrict__ Bl,
                                            float (*tile)[69],
                                            int ib, int t)
{
    const int k0 = (ib >> 5) * 64;          // 8 k-tiles
    const int c0 = (ib & 31) * 64;          // 32 col-tiles
    {
        const int r = t >> 2, cq = (t & 3) * 16;
#pragma unroll
        for (int j = 0; j < 4; ++j)
            *reinterpret_cast<float4*>(&tile[r][cq + j * 4]) =
                *reinterpret_cast<const float4*>(Wp + (size_t)(k0 + r) * NTOT + c0 + cq + j * 4);
    }
    __syncthreads();
    const int rr = t >> 2, kc2 = (t & 3) * 16;
    __align__(16) ushort h[16], l[16];
#pragma unroll
    for (int j = 0; j < 16; ++j) split_f16(tile[kc2 + j][rr], h[j], l[j]);
    ushort* dh = Bh + (size_t)(c0 + rr) * 512 + k0 + kc2;
    ushort* dl = Bl + (size_t)(c0 + rr) * 512 + k0 + kc2;
    *reinterpret_cast<ushort8*>(dh)     = *reinterpret_cast<const ushort8*>(h);
    *reinterpret_cast<ushort8*>(dh + 8) = *reinterpret_cast<const ushort8*>(h + 8);
    *reinterpret_cast<ushort8*>(dl)     = *reinterpret_cast<const ushort8*>(l);
    *reinterpret_cast<ushort8*>(dl + 8) = *reinterpret_cast<const ushort8*>(l + 8);
}

__global__ __launch_bounds__(256)
void popcode_prep(const float* __restrict__ x, const float* __restrict__ Wp,
                  ushort* __restrict__ Ah, ushort* __restrict__ Al,
                  ushort* __restrict__ Bh, ushort* __restrict__ Bl)
{
    __shared__ float tile[64][69];
    const int t = threadIdx.x;
    if (blockIdx.x < 256) conv_x_body(x, Ah, Al, blockIdx.x, t);
    else                  conv_w_body(Wp, Bh, Bl, tile, blockIdx.x - 256, t);
}

// ------------------------------------- K1: fused split-f16 MFMA GEMM + epi
// 1024 blocks (XCD-swizzled), 256 threads (4 waves). Tile 64x32, BK=32.
// LDS layout (33664 B): [buf0 12288][buf1 12288][Itile 64x34 f32][wlds 384B]
//   plane offsets in buf: Ah 0 (4KB), Al 4096, Bh 8192 (2KB), Bl 10240.
//   byte-LUT (12KB) built into buf0 region after the k-loop.
__global__ __launch_bounds__(256)
void popcode_fused(const ushort* __restrict__ Ah_g, const ushort* __restrict__ Al_g,
                   const ushort* __restrict__ Bh_g, const ushort* __restrict__ Bl_g,
                   const float* __restrict__ bp, const float* __restrict__ thrs,
                   const float* __restrict__ rateW, const float* __restrict__ rateB,
                   const float* __restrict__ c1w, const float* __restrict__ c1b,
                   const float* __restrict__ c2w, const float* __restrict__ c2b,
                   const float* __restrict__ fus, float* __restrict__ out)
{
    __shared__ __align__(16) char smem[33664];
    LDS_AS char* lds0 = (LDS_AS char*)smem;

    const int tid  = threadIdx.x;
    const int w    = tid >> 6;
    const int lane = tid & 63;

    // bijective XCD swizzle: 1024 = 8 XCDs x 128 contiguous wgs.
    const int wg = ((blockIdx.x & 7) << 7) | (blockIdx.x >> 3);
    const int b0 = (wg & 15) * 64;      // M tile (batch rows)
    const int c0 = (wg >> 4) * 32;      // N tile (neuron cols), 64 tiles

    const ushort* gbase = (w == 0) ? Ah_g : (w == 1) ? Al_g : (w == 2) ? Bh_g : Bl_g;
    const int     t0    = (w < 2) ? b0 : c0;
    const int     srow  = lane >> 2;
    const int     schk  = (lane & 3) * 8;     // in halves
    const int     poff  = (w < 2) ? (w * 4096) : (8192 + (w - 2) * 2048);

    const int wr = (w >> 1) * 32;       // quadrant row origin (A rows)
    const int wc = (w & 1) * 16;        // quadrant col origin (B cols)
    const int lr = lane & 15;
    const int lg = lane >> 4;

    const f32x4 zero = {0.f, 0.f, 0.f, 0.f};
    f32x4 acch[2] = {zero, zero};
    f32x4 accl[2] = {zero, zero};

    auto stage = [&](int buf, int kt) {
        const int koff = kt * 32 + schk;
        const int base = buf * 12288 + poff;
        if (w < 2) {
#pragma unroll
            for (int i = 0; i < 4; ++i) {
                const ushort* src = gbase + (size_t)(t0 + srow + 16 * i) * 512 + koff;
                const int loff = __builtin_amdgcn_readfirstlane(base + i * 1024);
                __builtin_amdgcn_global_load_lds((const GLOBAL_AS uint*)src,
                                                 (LDS_AS uint*)(lds0 + loff), 16, 0, 0);
            }
        } else {
#pragma unroll
            for (int i = 0; i < 2; ++i) {
                const ushort* src = gbase + (size_t)(t0 + srow + 16 * i) * 512 + koff;
                const int loff = __builtin_amdgcn_readfirstlane(base + i * 1024);
                __builtin_amdgcn_global_load_lds((const GLOBAL_AS uint*)src,
                                                 (LDS_AS uint*)(lds0 + loff), 16, 0, 0);
            }
        }
    };

    auto compute = [&](int buf) {
        const int rbase = buf * 12288;
        f16x8 ah[2], al[2], bh, bl;
#pragma unroll
        for (int m = 0; m < 2; ++m) {
            const int row = wr + m * 16 + lr;
            ah[m] = *reinterpret_cast<const f16x8*>(smem + rbase +        row * 64 + lg * 16);
            al[m] = *reinterpret_cast<const f16x8*>(smem + rbase + 4096 + row * 64 + lg * 16);
        }
        {
            const int col = wc + lr;
            bh = *reinterpret_cast<const f16x8*>(smem + rbase +  8192 + col * 64 + lg * 16);
            bl = *reinterpret_cast<const f16x8*>(smem + rbase + 10240 + col * 64 + lg * 16);
        }
#pragma unroll
        for (int m = 0; m < 2; ++m) {
            acch[m] = __builtin_amdgcn_mfma_f32_16x16x32_f16(ah[m], bh, acch[m], 0, 0, 0);
            accl[m] = __builtin_amdgcn_mfma_f32_16x16x32_f16(al[m], bh, accl[m], 0, 0, 0);
            accl[m] = __builtin_amdgcn_mfma_f32_16x16x32_f16(ah[m], bl, accl[m], 0, 0, 0);
        }
    };

    // ---- prologue ----
    float* wlds = (float*)(smem + 33280);
    if (tid < 96) wlds[tid] = c1w[tid];
    stage(0, 0);
    __syncthreads();

    // ---- GEMM k-loop ----
    for (int kt = 0; kt < 16; ++kt) {
        if (kt < 15) stage((kt + 1) & 1, kt + 1);
        compute(kt & 1);
        __syncthreads();
    }

    // ---- build byte LUT in buf0 region (staging dead now) ----
    float* lutf = (float*)smem;          // lut[tap][byte][chan], 3072 floats
    for (int e = tid; e < 3072; e += 256) {
        const int k    = e >> 10;
        const int byte = (e >> 2) & 255;
        const int c    = e & 3;
        float v = (k == 1) ? c1b[c] : 0.f;   // fold conv1 bias into tap 1
#pragma unroll
        for (int p = 0; p < 8; ++p)
            v = fmaf((float)((byte >> p) & 1), wlds[(c * 8 + p) * 3 + k], v);
        lutf[e] = v;
    }

    // ---- acc -> Itile (C/D layout: col = lane&15, row = (lane>>4)*4 + v) ----
    float* it = (float*)(smem + 24576);  // [64][34]
    const float s = 1.0f / 2048.0f;
#pragma unroll
    for (int m = 0; m < 2; ++m)
#pragma unroll
        for (int v = 0; v < 4; ++v)
            it[(wr + m * 16 + lg * 4 + v) * 34 + wc + lr] =
                acch[m][v] + accl[m][v] * s;
    __syncthreads();

    // ---- epilogue: exactly 1 neuron per thread (64 rows x 4 d) ----
    const int row  = tid >> 2;
    const int dloc = tid & 3;
    const int dg   = (c0 >> 3) + dloc;

    const float* ip  = it + row * 34 + dloc * 8;
    float thrv[8];
#pragma unroll
    for (int p = 0; p < 8; ++p) thrv[p] = thrs[p];

    float Iv[8], mem[8];
    bool  spk[8];
    {
        const float4 bv0 = *reinterpret_cast<const float4*>(bp + dg * 8);
        const float4 bv1 = *reinterpret_cast<const float4*>(bp + dg * 8 + 4);
        Iv[0] = ip[0] + bv0.x; Iv[1] = ip[1] + bv0.y;
        Iv[2] = ip[2] + bv0.z; Iv[3] = ip[3] + bv0.w;
        Iv[4] = ip[4] + bv1.x; Iv[5] = ip[5] + bv1.y;
        Iv[6] = ip[6] + bv1.z; Iv[7] = ip[7] + bv1.w;
    }
#pragma unroll
    for (int p = 0; p < 8; ++p) { mem[p] = 0.f; spk[p] = false; }

    // LIF, packing one byte per t (4 t per u32 word).
    // mem = beta*mem + I - reset*thr, reset from previous spike.
    unsigned wrd[8] = {0u, 0u, 0u, 0u, 0u, 0u, 0u, 0u};
#pragma unroll
    for (int t = 0; t < T_STEPS; ++t) {
        unsigned by = 0u;
#pragma unroll
        for (int p = 0; p < 8; ++p) {
            const float m2 = fmaf(0.95f, mem[p], Iv[p]);
            mem[p] = spk[p] ? (m2 - thrv[p]) : m2;
            spk[p] = mem[p] > thrv[p];
            by |= spk[p] ? (1u << p) : 0u;
        }
        wrd[t >> 2] |= by << (8 * (t & 3));
    }

    // rate branch: exact bit-plane popcount
    float rsum = 0.f;
#pragma unroll
    for (int p = 0; p < 8; ++p) {
        const unsigned m = 0x01010101u << p;
        int cnt = 0;
#pragma unroll
        for (int q = 0; q < 8; ++q) cnt += __popc(wrd[q] & m);
        rsum = fmaf((float)cnt, rateW[p], rsum);
    }

    // temporal conv: 3 byte-LUT reads per t
    float w2c[4];
#pragma unroll
    for (int c = 0; c < 4; ++c) w2c[c] = c2w[c];
    auto getb = [&](int t) -> unsigned {
        return (wrd[t >> 2] >> (8 * (t & 3))) & 255u;
    };
    float tacc = 0.f;
    unsigned bprev = 0u;
    unsigned bcur  = getb(0);
#pragma unroll
    for (int t = 0; t < T_STEPS; ++t) {
        const unsigned bnext = (t < 31) ? getb(t + 1) : 0u;
        const float4 fa = *reinterpret_cast<const float4*>(lutf + bprev * 4);
        const float4 fb = *reinterpret_cast<const float4*>(lutf + 1024 + bcur * 4);
        const float4 fc = *reinterpret_cast<const float4*>(lutf + 2048 + bnext * 4);
        const float h0_ = (fa.x + fb.x) + fc.x;
        const float h1_ = (fa.y + fb.y) + fc.y;
        const float h2_ = (fa.z + fb.z) + fc.z;
        const float h3_ = (fa.w + fb.w) + fc.w;
        tacc = fmaf(fmaxf(h0_, 0.f), w2c[0], tacc);
        tacc = fmaf(fmaxf(h1_, 0.f), w2c[1], tacc);
        tacc = fmaf(fmaxf(h2_, 0.f), w2c[2], tacc);
        tacc = fmaf(fmaxf(h3_, 0.f), w2c[3], tacc);
        bprev = bcur;
        bcur  = bnext;
    }

    // fusion weights (uniform scalars, loaded late)
    const float f0 = fus[0], f1 = fus[1];
    const float fm = fmaxf(f0, f1);
    const float e0 = __expf(f0 - fm), e1 = __expf(f1 - fm);
    const float inv = 1.f / (e0 + e1);

    const float rdec = rsum * (1.f / 32.f) + rateB[0];
    const float temp = tacc * (1.f / 32.f) + c2b[0];
    out[(b0 + row) * D_DIM + dg] = (e0 * inv) * rdec + (e1 * inv) * temp;
}

extern "C" void kernel_launch(void* const* d_in, const int* in_sizes, int n_in,
                              void* d_out, int out_size, void* d_ws, size_t ws_size,
                              hipStream_t stream) {
    const float* x     = (const float*)d_in[0];
    const float* Wp    = (const float*)d_in[1];
    const float* bp    = (const float*)d_in[2];
    const float* thrs  = (const float*)d_in[3];
    const float* rateW = (const float*)d_in[4];
    const float* rateB = (const float*)d_in[5];
    const float* c1w   = (const float*)d_in[6];
    const float* c1b   = (const float*)d_in[7];
    const float* c2w   = (const float*)d_in[8];
    const float* c2b   = (const float*)d_in[9];
    const float* fus   = (const float*)d_in[10];
    float* out = (float*)d_out;
    float* ws  = (float*)d_ws;

    // ws layout: Ah[1024*512]u16 | Al | Bh[2048*512]u16 | Bl   (12 MB)
    ushort* Ah = reinterpret_cast<ushort*>(ws);
    ushort* Al = Ah + 1024 * 512;
    ushort* Bh = Al + 1024 * 512;
    ushort* Bl = Bh + 2048 * 512;

    popcode_prep<<<dim3(512), dim3(256), 0, stream>>>(x, Wp, Ah, Al, Bh, Bl);
    popcode_fused<<<dim3(1024), dim3(256), 0, stream>>>(
        Ah, Al, Bh, Bl, bp, thrs, rateW, rateB, c1w, c1b, c2w, c2b, fus, out);
}

// Round 9
// 112.586 us; speedup vs baseline: 2.1974x; 1.0862x over previous
//
#include <hip/hip_runtime.h>

// PopulationCoding, round 20.
//  r19 post-mortem: spill fixed (WRITE 146->1.5MB). Fused 47.5us decomposed:
//  GEMM ds_reads 8-way conflicted (row*64 layout) ~19us + conv byte-LUT
//  random reads ~18us + VALU ~8. 4.97M conflicts ~= half GEMM, half conv.
//  r20: (1) fragment-ordered staging: stager lane loads (row=lane&15+16i,
//  chunk=lane>>4) so linear gload_lds dest puts fragment (q) at q*1024 +
//  lane*16 -> compute ds_read_b128 contiguous per wave = conflict-free,
//  same element->lane map (bit-identical MFMA). (2) 64x64 tile again
//  (512 blk, 4 waves, 2x2 frags): GEMM reads 393K->262K wave-instrs.
//  (3) keep byte-LUT conv (3 b128/t), LUT in dead buf0, lb(256), XCD swz.
// B=1024, IN=512, D=256, P=8, T=32. Output [1024,256] fp32.

constexpr int D_DIM   = 256;
constexpr int NTOT    = 2048;   // D*P
constexpr int T_STEPS = 32;

typedef _Float16 f16x8 __attribute__((ext_vector_type(8)));
typedef float    f32x4 __attribute__((ext_vector_type(4)));
typedef ushort   ushort8 __attribute__((ext_vector_type(8)));

#define GLOBAL_AS __attribute__((address_space(1)))
#define LDS_AS    __attribute__((address_space(3)))

__device__ __forceinline__ void split_f16(float v, ushort& h, ushort& l) {
    const _Float16 hf = (_Float16)v;
    const _Float16 lf = (_Float16)((v - (float)hf) * 2048.0f);  // lo pre-scaled 2^11
    h = __builtin_bit_cast(ushort, hf);
    l = __builtin_bit_cast(ushort, lf);
}

// ------------------------------------------------- K0: split-f16 conversion
__device__ __forceinline__ void conv_x_body(const float* __restrict__ x,
                                            ushort* __restrict__ Ah,
                                            ushort* __restrict__ Al,
                                            int blk, int t)
{
    const int idx = (blk * 256 + t) * 8;
    float v[8];
    *reinterpret_cast<float4*>(v)     = *reinterpret_cast<const float4*>(x + idx);
    *reinterpret_cast<float4*>(v + 4) = *reinterpret_cast<const float4*>(x + idx + 4);
    __align__(16) ushort h[8], l[8];
#pragma unroll
    for (int j = 0; j < 8; ++j) split_f16(v[j], h[j], l[j]);
    *reinterpret_cast<ushort8*>(Ah + idx) = *reinterpret_cast<const ushort8*>(h);
    *reinterpret_cast<ushort8*>(Al + idx) = *reinterpret_cast<const ushort8*>(l);
}

__device__ __forceinline__ void conv_w_body(const float* __restrict__ Wp,
                                            ushort* __restrict__ Bh,
                                            ushort* __restrict__ Bl,
                                            float (*tile)[69],
                                            int ib, int t)
{
    const int k0 = (ib >> 5) * 64;          // 8 k-tiles
    const int c0 = (ib & 31) * 64;          // 32 col-tiles
    {
        const int r = t >> 2, cq = (t & 3) * 16;
#pragma unroll
        for (int j = 0; j < 4; ++j)
            *reinterpret_cast<float4*>(&tile[r][cq + j * 4]) =
                *reinterpret_cast<const float4*>(Wp + (size_t)(k0 + r) * NTOT + c0 + cq + j * 4);
    }
    __syncthreads();
    const int rr = t >> 2, kc2 = (t & 3) * 16;
    __align__(16) ushort h[16], l[16];
#pragma unroll
    for (int j = 0; j < 16; ++j) split_f16(tile[kc2 + j][rr], h[j], l[j]);
    ushort* dh = Bh + (size_t)(c0 + rr) * 512 + k0 + kc2;
    ushort* dl = Bl + (size_t)(c0 + rr) * 512 + k0 + kc2;
    *reinterpret_cast<ushort8*>(dh)     = *reinterpret_cast<const ushort8*>(h);
    *reinterpret_cast<ushort8*>(dh + 8) = *reinterpret_cast<const ushort8*>(h + 8);
    *reinterpret_cast<ushort8*>(dl)     = *reinterpret_cast<const ushort8*>(l);
    *reinterpret_cast<ushort8*>(dl + 8) = *reinterpret_cast<const ushort8*>(l + 8);
}

__global__ __launch_bounds__(256)
void popcode_prep(const float* __restrict__ x, const float* __restrict__ Wp,
                  ushort* __restrict__ Ah, ushort* __restrict__ Al,
                  ushort* __restrict__ Bh, ushort* __restrict__ Bl)
{
    __shared__ float tile[64][69];
    const int t = threadIdx.x;
    if (blockIdx.x < 256) conv_x_body(x, Ah, Al, blockIdx.x, t);
    else                  conv_w_body(Wp, Bh, Bl, tile, blockIdx.x - 256, t);
}

// ------------------------------------- K1: fused split-f16 MFMA GEMM + epi
// 512 blocks (XCD-swizzled), 256 threads (4 waves). Tile 64x64, BK=32.
// LDS (49792 B): [buf0 16K][buf1 16K][Itile 64x65 f32 16640][wlds 384]
//   per-buf planes: Ah 0, Al 4096, Bh 8192, Bl 12288 (4KB each).
//   Fragment-ordered: plane element (row=q*16+lr, kchunk lg) at
//   q*1024 + lg*256 + lr*16 = q*1024 + lane*16  (lane = lr + 16*lg).
//   byte-LUT (12KB) built into buf0 after the k-loop.
__global__ __launch_bounds__(256)
void popcode_fused(const ushort* __restrict__ Ah_g, const ushort* __restrict__ Al_g,
                   const ushort* __restrict__ Bh_g, const ushort* __restrict__ Bl_g,
                   const float* __restrict__ bp, const float* __restrict__ thrs,
                   const float* __restrict__ rateW, const float* __restrict__ rateB,
                   const float* __restrict__ c1w, const float* __restrict__ c1b,
                   const float* __restrict__ c2w, const float* __restrict__ c2b,
                   const float* __restrict__ fus, float* __restrict__ out)
{
    __shared__ __align__(16) char smem[49792];
    LDS_AS char* lds0 = (LDS_AS char*)smem;

    const int tid  = threadIdx.x;
    const int w    = tid >> 6;          // wave id = staged plane id
    const int lane = tid & 63;

    // bijective XCD swizzle: 512 = 8 XCDs x 64 contiguous wgs.
    const int wg = (blockIdx.x & 7) * 64 + (blockIdx.x >> 3);
    const int b0 = (wg & 15) * 64;      // M tile (batch rows)
    const int c0 = (wg >> 4) * 64;      // N tile (neuron cols)

    const ushort* gbase = (w == 0) ? Ah_g : (w == 1) ? Al_g : (w == 2) ? Bh_g : Bl_g;
    const int     t0    = (w < 2) ? b0 : c0;
    const int     srow  = lane & 15;          // fragment-ordered staging
    const int     schk  = (lane >> 4) * 8;    // k-chunk, in halves

    const int wr = (w >> 1) * 32;       // quadrant row origin
    const int wc = (w & 1) * 32;        // quadrant col origin
    const int lr = lane & 15;
    const int lg = lane >> 4;

    const f32x4 zero = {0.f, 0.f, 0.f, 0.f};
    f32x4 acch[2][2] = {{zero, zero}, {zero, zero}};
    f32x4 accl[2][2] = {{zero, zero}, {zero, zero}};

    auto stage = [&](int buf, int kt) {
        const int koff = kt * 32 + schk;
#pragma unroll
        for (int i = 0; i < 4; ++i) {
            const ushort* src = gbase + (size_t)(t0 + srow + 16 * i) * 512 + koff;
            const int loff = __builtin_amdgcn_readfirstlane(buf * 16384 + w * 4096 + i * 1024);
            __builtin_amdgcn_global_load_lds((const GLOBAL_AS uint*)src,
                                             (LDS_AS uint*)(lds0 + loff), 16, 0, 0);
        }
    };

    auto compute = [&](int buf) {
        const int rbase = buf * 16384 + lane * 16;
        f16x8 ah[2], al[2], bh[2], bl[2];
#pragma unroll
        for (int m = 0; m < 2; ++m) {
            const int qa = (w >> 1) * 2 + m;          // row-group
            ah[m] = *reinterpret_cast<const f16x8*>(smem + rbase +        qa * 1024);
            al[m] = *reinterpret_cast<const f16x8*>(smem + rbase + 4096 + qa * 1024);
        }
#pragma unroll
        for (int n = 0; n < 2; ++n) {
            const int qb = (w & 1) * 2 + n;           // col-group
            bh[n] = *reinterpret_cast<const f16x8*>(smem + rbase +  8192 + qb * 1024);
            bl[n] = *reinterpret_cast<const f16x8*>(smem + rbase + 12288 + qb * 1024);
        }
#pragma unroll
        for (int m = 0; m < 2; ++m)
#pragma unroll
            for (int n = 0; n < 2; ++n) {
                acch[m][n] = __builtin_amdgcn_mfma_f32_16x16x32_f16(ah[m], bh[n], acch[m][n], 0, 0, 0);
                accl[m][n] = __builtin_amdgcn_mfma_f32_16x16x32_f16(al[m], bh[n], accl[m][n], 0, 0, 0);
                accl[m][n] = __builtin_amdgcn_mfma_f32_16x16x32_f16(ah[m], bl[n], accl[m][n], 0, 0, 0);
            }
    };

    // ---- prologue ----
    float* wlds = (float*)(smem + 49408);
    if (tid < 96) wlds[tid] = c1w[tid];
    stage(0, 0);
    __syncthreads();

    // ---- GEMM k-loop ----
    for (int kt = 0; kt < 16; ++kt) {
        if (kt < 15) stage((kt + 1) & 1, kt + 1);
        compute(kt & 1);
        __syncthreads();
    }

    // ---- build byte LUT in buf0 region (staging dead now) ----
    float* lutf = (float*)smem;          // lut[tap][byte][chan], 3072 floats
    for (int e = tid; e < 3072; e += 256) {
        const int k    = e >> 10;
        const int byte = (e >> 2) & 255;
        const int c    = e & 3;
        float v = (k == 1) ? c1b[c] : 0.f;   // fold conv1 bias into tap 1
#pragma unroll
        for (int p = 0; p < 8; ++p)
            v = fmaf((float)((byte >> p) & 1), wlds[(c * 8 + p) * 3 + k], v);
        lutf[e] = v;
    }

    // ---- acc -> Itile (C/D layout: col = lane&15, row = (lane>>4)*4 + v) ----
    float* it = (float*)(smem + 32768);  // [64][65]
    const float s = 1.0f / 2048.0f;
#pragma unroll
    for (int m = 0; m < 2; ++m)
#pragma unroll
        for (int n = 0; n < 2; ++n)
#pragma unroll
            for (int v = 0; v < 4; ++v)
                it[(wr + m * 16 + lg * 4 + v) * 65 + wc + n * 16 + lr] =
                    acch[m][n][v] + accl[m][n][v] * s;
    __syncthreads();

    // ---- uniform scalars ----
    float thrv[8];
#pragma unroll
    for (int p = 0; p < 8; ++p) thrv[p] = thrs[p];
    float w2c[4];
#pragma unroll
    for (int c = 0; c < 4; ++c) w2c[c] = c2w[c];
    const float f0 = fus[0], f1 = fus[1];
    const float fm = fmaxf(f0, f1);
    const float e0 = __expf(f0 - fm), e1 = __expf(f1 - fm);
    const float inv = 1.f / (e0 + e1);
    const float fw0 = e0 * inv, fw1 = e1 * inv;
    const float rb_ = rateB[0];
    const float bb2 = c2b[0];

    // ---- epilogue: 2 neurons per thread (row = tid>>2, d = tid&3, +4) ----
    const int row = tid >> 2;
    for (int n2 = 0; n2 < 2; ++n2) {
        const int dloc = (tid & 3) + n2 * 4;
        const int dg   = (c0 >> 3) + dloc;

        const float* ip = it + row * 65 + dloc * 8;
        float Iv[8], mem[8];
        bool  spk[8];
        {
            const float4 bv0 = *reinterpret_cast<const float4*>(bp + dg * 8);
            const float4 bv1 = *reinterpret_cast<const float4*>(bp + dg * 8 + 4);
            Iv[0] = ip[0] + bv0.x; Iv[1] = ip[1] + bv0.y;
            Iv[2] = ip[2] + bv0.z; Iv[3] = ip[3] + bv0.w;
            Iv[4] = ip[4] + bv1.x; Iv[5] = ip[5] + bv1.y;
            Iv[6] = ip[6] + bv1.z; Iv[7] = ip[7] + bv1.w;
        }
#pragma unroll
        for (int p = 0; p < 8; ++p) { mem[p] = 0.f; spk[p] = false; }

        // LIF, packing one byte per t (4 t per u32 word)
        unsigned wrd[8] = {0u, 0u, 0u, 0u, 0u, 0u, 0u, 0u};
#pragma unroll
        for (int t = 0; t < T_STEPS; ++t) {
            unsigned by = 0u;
#pragma unroll
            for (int p = 0; p < 8; ++p) {
                const float m2 = fmaf(0.95f, mem[p], Iv[p]);
                mem[p] = spk[p] ? (m2 - thrv[p]) : m2;
                spk[p] = mem[p] > thrv[p];
                by |= spk[p] ? (1u << p) : 0u;
            }
            wrd[t >> 2] |= by << (8 * (t & 3));
        }

        // rate branch: exact bit-plane popcount
        float rsum = 0.f;
#pragma unroll
        for (int p = 0; p < 8; ++p) {
            const unsigned m = 0x01010101u << p;
            int cnt = 0;
#pragma unroll
            for (int q = 0; q < 8; ++q) cnt += __popc(wrd[q] & m);
            rsum = fmaf((float)cnt, rateW[p], rsum);
        }

        // temporal conv: 3 byte-LUT reads per t
        auto getb = [&](int t) -> unsigned {
            return (wrd[t >> 2] >> (8 * (t & 3))) & 255u;
        };
        float tacc = 0.f;
        unsigned bprev = 0u;
        unsigned bcur  = getb(0);
#pragma unroll
        for (int t = 0; t < T_STEPS; ++t) {
            const unsigned bnext = (t < 31) ? getb(t + 1) : 0u;
            const float4 fa = *reinterpret_cast<const float4*>(lutf + bprev * 4);
            const float4 fb = *reinterpret_cast<const float4*>(lutf + 1024 + bcur * 4);
            const float4 fc = *reinterpret_cast<const float4*>(lutf + 2048 + bnext * 4);
            const float h0_ = (fa.x + fb.x) + fc.x;
            const float h1_ = (fa.y + fb.y) + fc.y;
            const float h2_ = (fa.z + fb.z) + fc.z;
            const float h3_ = (fa.w + fb.w) + fc.w;
            tacc = fmaf(fmaxf(h0_, 0.f), w2c[0], tacc);
            tacc = fmaf(fmaxf(h1_, 0.f), w2c[1], tacc);
            tacc = fmaf(fmaxf(h2_, 0.f), w2c[2], tacc);
            tacc = fmaf(fmaxf(h3_, 0.f), w2c[3], tacc);
            bprev = bcur;
            bcur  = bnext;
        }

        const float rdec = rsum * (1.f / 32.f) + rb_;
        const float temp = tacc * (1.f / 32.f) + bb2;
        out[(b0 + row) * D_DIM + dg] = fw0 * rdec + fw1 * temp;
    }
}

extern "C" void kernel_launch(void* const* d_in, const int* in_sizes, int n_in,
                              void* d_out, int out_size, void* d_ws, size_t ws_size,
                              hipStream_t stream) {
    const float* x     = (const float*)d_in[0];
    const float* Wp    = (const float*)d_in[1];
    const float* bp    = (const float*)d_in[2];
    const float* thrs  = (const float*)d_in[3];
    const float* rateW = (const float*)d_in[4];
    const float* rateB = (const float*)d_in[5];
    const float* c1w   = (const float*)d_in[6];
    const float* c1b   = (const float*)d_in[7];
    const float* c2w   = (const float*)d_in[8];
    const float* c2b   = (const float*)d_in[9];
    const float* fus   = (const float*)d_in[10];
    float* out = (float*)d_out;
    float* ws  = (float*)d_ws;

    // ws layout: Ah[1024*512]u16 | Al | Bh[2048*512]u16 | Bl   (12 MB)
    ushort* Ah = reinterpret_cast<ushort*>(ws);
    ushort* Al = Ah + 1024 * 512;
    ushort* Bh = Al + 1024 * 512;
    ushort* Bl = Bh + 2048 * 512;

    popcode_prep<<<dim3(512), dim3(256), 0, stream>>>(x, Wp, Ah, Al, Bh, Bl);
    popcode_fused<<<dim3(512), dim3(256), 0, stream>>>(
        Ah, Al, Bh, Bl, bp, thrs, rateW, rateB, c1w, c1b, c2w, c2b, fus, out);
}